// Round 2
// baseline (8350.475 us; speedup 1.0000x reference)
//
#include <hip/hip_runtime.h>
#include <math.h>

#define BATCH 4
#define P 3072
#define NROW (BATCH * P)      // 12288
#define RCH 24                // row chunks for v partial pass (128 rows each)
#define MAXIT 50

__device__ inline float waveReduceSum(float v) {
#pragma unroll
  for (int off = 32; off > 0; off >>= 1) v += __shfl_xor(v, off, 64);
  return v;
}
__device__ inline float waveReduceMax(float v) {
#pragma unroll
  for (int off = 32; off > 0; off >>= 1) v = fmaxf(v, __shfl_xor(v, off, 64));
  return v;
}

// x2[b][i] = sum_k x[b][i][k]^2 ; y2 likewise. 8 rows per 256-thread block.
__global__ __launch_bounds__(256) void sq_kernel(const float* __restrict__ x,
                                                 const float* __restrict__ y,
                                                 float* __restrict__ x2,
                                                 float* __restrict__ y2) {
  int t = threadIdx.x;
  int row = blockIdx.x * 8 + (t >> 5);   // 0..24575
  int k = t & 31;
  const float* src = x;
  float* dst = x2;
  int r = row;
  if (row >= NROW) { src = y; dst = y2; r = row - NROW; }
  float vv = src[(size_t)r * 32 + k];
  float sq = vv * vv;
#pragma unroll
  for (int off = 16; off > 0; off >>= 1) sq += __shfl_xor(sq, off, 32);
  if (k == 0) dst[r] = sq;
}

// C[b][i][j] = x2_i + y2_j - 2 * dot(x_i, y_j). 64x64 tile per block.
__global__ __launch_bounds__(256) void c_kernel(const float* __restrict__ x,
                                                const float* __restrict__ y,
                                                const float* __restrict__ x2,
                                                const float* __restrict__ y2,
                                                float* __restrict__ C) {
  __shared__ float xs[64][33];
  __shared__ float ys[64][33];
  int t = threadIdx.x;
  int b = blockIdx.z;
  int i0 = blockIdx.x * 64;
  int j0 = blockIdx.y * 64;
  const float4* xg = (const float4*)(x + ((size_t)b * P + i0) * 32);
  const float4* yg = (const float4*)(y + ((size_t)b * P + j0) * 32);
#pragma unroll
  for (int k = 0; k < 2; ++k) {
    int f4 = t + k * 256;              // 0..511 over 64x32 tile
    int row = f4 >> 3;
    int col = (f4 & 7) << 2;
    float4 xv = xg[f4];
    xs[row][col] = xv.x; xs[row][col + 1] = xv.y; xs[row][col + 2] = xv.z; xs[row][col + 3] = xv.w;
    float4 yv = yg[f4];
    ys[row][col] = yv.x; ys[row][col + 1] = yv.y; ys[row][col + 2] = yv.z; ys[row][col + 3] = yv.w;
  }
  __syncthreads();
  int ti = t >> 4, tj = t & 15;
  int ib = ti * 4, jb = tj * 4;
  float acc[4][4];
#pragma unroll
  for (int a = 0; a < 4; ++a)
#pragma unroll
    for (int bb = 0; bb < 4; ++bb) acc[a][bb] = 0.f;
#pragma unroll 8
  for (int k = 0; k < 32; ++k) {
    float xa[4], yb[4];
#pragma unroll
    for (int a = 0; a < 4; ++a) xa[a] = xs[ib + a][k];
#pragma unroll
    for (int bb = 0; bb < 4; ++bb) yb[bb] = ys[jb + bb][k];
#pragma unroll
    for (int a = 0; a < 4; ++a)
#pragma unroll
      for (int bb = 0; bb < 4; ++bb) acc[a][bb] = fmaf(xa[a], yb[bb], acc[a][bb]);
  }
  float y2r[4];
#pragma unroll
  for (int bb = 0; bb < 4; ++bb) y2r[bb] = y2[b * P + j0 + jb + bb];
#pragma unroll
  for (int a = 0; a < 4; ++a) {
    float x2r = x2[b * P + i0 + ib + a];
    float4 o;
    o.x = x2r + y2r[0] - 2.f * acc[a][0];
    o.y = x2r + y2r[1] - 2.f * acc[a][1];
    o.z = x2r + y2r[2] - 2.f * acc[a][2];
    o.w = x2r + y2r[3] - 2.f * acc[a][3];
    float* rowp = C + ((size_t)b * P + i0 + ib + a) * P + j0;
    ((float4*)rowp)[tj] = o;
  }
}

// u-update: one block per (b,i) row. u_new = eps*log_mu - eps*LSE_j((v_j - C_ij)/eps)
__global__ __launch_bounds__(256) void u_kernel(const float* __restrict__ C,
                                                const float* __restrict__ v,
                                                float* __restrict__ u,
                                                float* __restrict__ errbuf,
                                                const int* __restrict__ done_arr,
                                                int it, float log_mu) {
  if (done_arr[it]) return;
  int bi = blockIdx.x;                 // b*P + i
  int b = bi / P;
  const float4* Crow = (const float4*)(C + (size_t)bi * P);
  const float4* v4 = (const float4*)(v + (size_t)b * P);
  int t = threadIdx.x;
  float a[12];
  float m = -1e30f;
#pragma unroll
  for (int k = 0; k < 3; ++k) {
    float4 c = Crow[t + k * 256];
    float4 vv = v4[t + k * 256];
    a[4 * k + 0] = (vv.x - c.x) * 10.0f;
    a[4 * k + 1] = (vv.y - c.y) * 10.0f;
    a[4 * k + 2] = (vv.z - c.z) * 10.0f;
    a[4 * k + 3] = (vv.w - c.w) * 10.0f;
    m = fmaxf(m, fmaxf(fmaxf(a[4 * k], a[4 * k + 1]), fmaxf(a[4 * k + 2], a[4 * k + 3])));
  }
  m = waveReduceMax(m);
  __shared__ float redm[4];
  __shared__ float reds[4];
  int wid = t >> 6;
  if ((t & 63) == 0) redm[wid] = m;
  __syncthreads();
  float M = fmaxf(fmaxf(redm[0], redm[1]), fmaxf(redm[2], redm[3]));
  float s = 0.f;
#pragma unroll
  for (int k = 0; k < 12; ++k) s += __expf(a[k] - M);
  s = waveReduceSum(s);
  if ((t & 63) == 0) reds[wid] = s;
  __syncthreads();
  if (t == 0) {
    float S = reds[0] + reds[1] + reds[2] + reds[3];
    float L = M + __logf(S);
    float un = 0.1f * (log_mu - L);
    float uo = u[bi];
    u[bi] = un;
    errbuf[bi] = fabsf(un - uo);
  }
}

// v partial pass + fused combine (last-block pattern) + fused convergence check.
// Block = (b, col-tile of 256, row-chunk of 128). Online LSE, 4-way ILP.
__global__ __launch_bounds__(256) void vpart_kernel(const float* __restrict__ C,
                                                    const float* __restrict__ u,
                                                    float* __restrict__ vpart,
                                                    float* __restrict__ v,
                                                    const float* __restrict__ errbuf,
                                                    int* __restrict__ done_arr,
                                                    int* __restrict__ cnt,
                                                    int it, float log_nu) {
  int blk = blockIdx.x;
  int b = blk / (12 * RCH);
  int rem = blk - b * (12 * RCH);
  int ct = rem / RCH;
  int rc = rem - ct * RCH;
  int t = threadIdx.x;
  int col = ct * 256 + t;
  int dn = done_arr[it];

  if (!dn) {
    int i0 = rc * 128;
    const float* Cp = C + ((size_t)b * P + i0) * P + col;
    const float* ub = u + b * P + i0;
    float m0 = -1e30f, m1 = -1e30f, m2 = -1e30f, m3 = -1e30f;
    float s0 = 0.f, s1 = 0.f, s2 = 0.f, s3 = 0.f;
    for (int r = 0; r < 32; ++r) {
      float c0 = Cp[(size_t)r * P];
      float c1 = Cp[(size_t)(r + 32) * P];
      float c2 = Cp[(size_t)(r + 64) * P];
      float c3 = Cp[(size_t)(r + 96) * P];
      float a0 = (ub[r] - c0) * 10.f;
      float a1 = (ub[r + 32] - c1) * 10.f;
      float a2 = (ub[r + 64] - c2) * 10.f;
      float a3 = (ub[r + 96] - c3) * 10.f;
      float n0 = fmaxf(m0, a0); s0 = s0 * __expf(m0 - n0) + __expf(a0 - n0); m0 = n0;
      float n1 = fmaxf(m1, a1); s1 = s1 * __expf(m1 - n1) + __expf(a1 - n1); m1 = n1;
      float n2 = fmaxf(m2, a2); s2 = s2 * __expf(m2 - n2) + __expf(a2 - n2); m2 = n2;
      float n3 = fmaxf(m3, a3); s3 = s3 * __expf(m3 - n3) + __expf(a3 - n3); m3 = n3;
    }
    float M = fmaxf(fmaxf(m0, m1), fmaxf(m2, m3));
    float s = s0 * __expf(m0 - M) + s1 * __expf(m1 - M) +
              s2 * __expf(m2 - M) + s3 * __expf(m3 - M);
    vpart[((size_t)(b * RCH + rc)) * P + col] = M + __logf(s);
    __threadfence();   // make partial visible before ticket
  }

  // last-block-finishes ticket per (it, b, ct)
  __shared__ int isLast;
  if (t == 0) {
    int ticket = atomicAdd(&cnt[it * 48 + b * 12 + ct], 1);
    isLast = (ticket == RCH - 1) ? 1 : 0;
  }
  __syncthreads();
  if (!isLast) return;
  __threadfence();     // acquire: see all partials

  if (!dn) {
    float vals[RCH];
    float m = -1e30f;
#pragma unroll
    for (int r = 0; r < RCH; ++r) {
      vals[r] = vpart[((size_t)(b * RCH + r)) * P + col];
      m = fmaxf(m, vals[r]);
    }
    float s = 0.f;
#pragma unroll
    for (int r = 0; r < RCH; ++r) s += __expf(vals[r] - m);
    float L = m + __logf(s);
    v[b * P + col] = 0.1f * (log_nu - L);
  }

  if (b == 0 && ct == 0) {
    // convergence check for next iteration
    __shared__ float red[4];
    float loc = 0.f;
    if (!dn) {
      for (int idx = t; idx < NROW; idx += 256) loc += errbuf[idx];
    }
    loc = waveReduceSum(loc);
    if ((t & 63) == 0) red[t >> 6] = loc;
    __syncthreads();
    if (t == 0) {
      float tot = red[0] + red[1] + red[2] + red[3];
      done_arr[it + 1] = (dn || (tot * 0.25f < 0.1f)) ? 1 : 0;
    }
  }
}

// pi = exp((-C + u_i + v_j)/eps); fused cost via per-block atomicAdd
__global__ __launch_bounds__(256) void pi_kernel(const float* __restrict__ C,
                                                 const float* __restrict__ u,
                                                 const float* __restrict__ v,
                                                 float* __restrict__ pi,
                                                 float* __restrict__ cost) {
  int bi = blockIdx.x;
  int b = bi / P;
  float ui = u[bi];
  const float4* Crow = (const float4*)(C + (size_t)bi * P);
  const float4* v4 = (const float4*)(v + (size_t)b * P);
  float4* pirow = (float4*)(pi + (size_t)bi * P);
  int t = threadIdx.x;
  float acc = 0.f;
#pragma unroll
  for (int k = 0; k < 3; ++k) {
    float4 c = Crow[t + k * 256];
    float4 vv = v4[t + k * 256];
    float4 p;
    p.x = __expf((ui + vv.x - c.x) * 10.f);
    p.y = __expf((ui + vv.y - c.y) * 10.f);
    p.z = __expf((ui + vv.z - c.z) * 10.f);
    p.w = __expf((ui + vv.w - c.w) * 10.f);
    pirow[t + k * 256] = p;
    acc += p.x * c.x + p.y * c.y + p.z * c.z + p.w * c.w;
  }
  acc = waveReduceSum(acc);
  __shared__ float red[4];
  if ((t & 63) == 0) red[t >> 6] = acc;
  __syncthreads();
  if (t == 0) atomicAdd(&cost[b], red[0] + red[1] + red[2] + red[3]);
}

extern "C" void kernel_launch(void* const* d_in, const int* in_sizes, int n_in,
                              void* d_out, int out_size, void* d_ws, size_t ws_size,
                              hipStream_t stream) {
  (void)in_sizes; (void)n_in; (void)out_size; (void)ws_size;
  const float* x = (const float*)d_in[0];
  const float* y = (const float*)d_in[1];
  float* out = (float*)d_out;
  float* cost = out;                          // [4]
  float* pi = out + 4;                        // [4*3072*3072]
  float* C = pi + (size_t)BATCH * P * P;      // [4*3072*3072]

  // workspace layout (floats):
  float* u = (float*)d_ws;                    // 12288
  float* v = u + NROW;                        // 12288   (ends 24576)
  int* done_arr = (int*)(v + NROW);           // 64 ints          @24576
  int* cnt = done_arr + 64;                   // 50*48=2400 -> 2432 @24640 (ends 27072)
  float* errbuf = (float*)(cnt + 2432);       // 12288  @27072 (aliases nothing)
  float* x2 = errbuf + NROW;                  // 12288  @39360
  float* y2 = x2 + NROW;                      // 12288  @51648
  float* vpart = y2 + NROW;                   // 4*24*3072=294912 @63936 (ends 358848)

  // zero u, v, done_arr, cnt (harness poisons ws each call); zero cost in d_out
  hipMemsetAsync(d_ws, 0, (size_t)27072 * sizeof(float), stream);
  hipMemsetAsync(cost, 0, 4 * sizeof(float), stream);

  float log_mu = logf(1.0f / 3072.0f + 1e-8f);   // log_nu identical (P1==P2)

  sq_kernel<<<3072, 256, 0, stream>>>(x, y, x2, y2);
  c_kernel<<<dim3(48, 48, 4), 256, 0, stream>>>(x, y, x2, y2, C);

  for (int it = 0; it < MAXIT; ++it) {
    u_kernel<<<NROW, 256, 0, stream>>>(C, v, u, errbuf, done_arr, it, log_mu);
    vpart_kernel<<<BATCH * 12 * RCH, 256, 0, stream>>>(C, u, vpart, v, errbuf,
                                                       done_arr, cnt, it, log_mu);
  }

  pi_kernel<<<NROW, 256, 0, stream>>>(C, u, v, pi, cost);
}

// Round 3
// 3712.857 us; speedup vs baseline: 2.2491x; 2.2491x over previous
//
#include <hip/hip_runtime.h>
#include <math.h>

#define BATCH 4
#define P 3072
#define NROW (BATCH * P)      // 12288
#define MAXIT 50
#define SPLIT_N (BATCH * P * 32)   // 393216 elements per split array

typedef __attribute__((ext_vector_type(8))) short bf16x8;
typedef __attribute__((ext_vector_type(4))) float f32x4;

__device__ inline float waveReduceSum(float v) {
#pragma unroll
  for (int off = 32; off > 0; off >>= 1) v += __shfl_xor(v, off, 64);
  return v;
}

__device__ inline unsigned short bf16_rtne(float f) {
  unsigned ub = __float_as_uint(f);
  return (unsigned short)((ub + 0x7FFFu + ((ub >> 16) & 1u)) >> 16);
}

// split x,y into bf16 hi/lo pairs (RTNE both): x = xh + xl to ~16-bit mantissa
__global__ __launch_bounds__(256) void split_kernel(const float* __restrict__ x,
                                                    const float* __restrict__ y,
                                                    short* __restrict__ xh,
                                                    short* __restrict__ xl,
                                                    short* __restrict__ yh,
                                                    short* __restrict__ yl) {
  int idx = blockIdx.x * 256 + threadIdx.x;   // 0 .. 2*SPLIT_N-1
  const float* src = x;
  short* dh = xh; short* dl = xl;
  int e = idx;
  if (idx >= SPLIT_N) { src = y; dh = yh; dl = yl; e = idx - SPLIT_N; }
  float f = src[e];
  unsigned short hb = bf16_rtne(f);
  float hf = __uint_as_float((unsigned)hb << 16);
  float lf = f - hf;
  unsigned short lb = bf16_rtne(lf);
  dh[e] = (short)hb;
  dl[e] = (short)lb;
}

// x2[b][i] = |x_i|^2 etc; also gx=-10*x2, gy=-10*y2, wu0=-10*x2, wv0=-10*y2
__global__ __launch_bounds__(256) void sq_kernel(const float* __restrict__ x,
                                                 const float* __restrict__ y,
                                                 float* __restrict__ x2,
                                                 float* __restrict__ y2,
                                                 float* __restrict__ gx,
                                                 float* __restrict__ gy,
                                                 float* __restrict__ wu,
                                                 float* __restrict__ wv) {
  int t = threadIdx.x;
  int row = blockIdx.x * 8 + (t >> 5);   // 0..24575
  int k = t & 31;
  const float* src = x;
  int r = row;
  bool isx = true;
  if (row >= NROW) { src = y; r = row - NROW; isx = false; }
  float vv = src[(size_t)r * 32 + k];
  float sq = vv * vv;
#pragma unroll
  for (int off = 16; off > 0; off >>= 1) sq += __shfl_xor(sq, off, 32);
  if (k == 0) {
    if (isx) { x2[r] = sq; gx[r] = -10.f * sq; wu[r] = -10.f * sq; }
    else     { y2[r] = sq; gy[r] = -10.f * sq; wv[r] = -10.f * sq; }
  }
}

// C[b][i][j] = x2_i + y2_j - 2 * dot(x_i, y_j), exact fp32 (C is an output).
__global__ __launch_bounds__(256) void c_kernel(const float* __restrict__ x,
                                                const float* __restrict__ y,
                                                const float* __restrict__ x2,
                                                const float* __restrict__ y2,
                                                float* __restrict__ C) {
  __shared__ float xs[64][33];
  __shared__ float ys[64][33];
  int t = threadIdx.x;
  int b = blockIdx.z;
  int i0 = blockIdx.x * 64;
  int j0 = blockIdx.y * 64;
  const float4* xg = (const float4*)(x + ((size_t)b * P + i0) * 32);
  const float4* yg = (const float4*)(y + ((size_t)b * P + j0) * 32);
#pragma unroll
  for (int k = 0; k < 2; ++k) {
    int f4 = t + k * 256;
    int row = f4 >> 3;
    int col = (f4 & 7) << 2;
    float4 xv = xg[f4];
    xs[row][col] = xv.x; xs[row][col + 1] = xv.y; xs[row][col + 2] = xv.z; xs[row][col + 3] = xv.w;
    float4 yv = yg[f4];
    ys[row][col] = yv.x; ys[row][col + 1] = yv.y; ys[row][col + 2] = yv.z; ys[row][col + 3] = yv.w;
  }
  __syncthreads();
  int ti = t >> 4, tj = t & 15;
  int ib = ti * 4, jb = tj * 4;
  float acc[4][4];
#pragma unroll
  for (int a = 0; a < 4; ++a)
#pragma unroll
    for (int bb = 0; bb < 4; ++bb) acc[a][bb] = 0.f;
#pragma unroll 8
  for (int k = 0; k < 32; ++k) {
    float xa[4], yb[4];
#pragma unroll
    for (int a = 0; a < 4; ++a) xa[a] = xs[ib + a][k];
#pragma unroll
    for (int bb = 0; bb < 4; ++bb) yb[bb] = ys[jb + bb][k];
#pragma unroll
    for (int a = 0; a < 4; ++a)
#pragma unroll
      for (int bb = 0; bb < 4; ++bb) acc[a][bb] = fmaf(xa[a], yb[bb], acc[a][bb]);
  }
  float y2r[4];
#pragma unroll
  for (int bb = 0; bb < 4; ++bb) y2r[bb] = y2[b * P + j0 + jb + bb];
#pragma unroll
  for (int a = 0; a < 4; ++a) {
    float x2r = x2[b * P + i0 + ib + a];
    float4 o;
    o.x = x2r + y2r[0] - 2.f * acc[a][0];
    o.y = x2r + y2r[1] - 2.f * acc[a][1];
    o.z = x2r + y2r[2] - 2.f * acc[a][2];
    o.w = x2r + y2r[3] - 2.f * acc[a][3];
    float* rowp = C + ((size_t)b * P + i0 + ib + a) * P + j0;
    ((float4*)rowp)[tj] = o;
  }
}

// u-update via MFMA recompute of C. Block = (16 rows of batch); 4 waves split j.
// a_ij = (v_j - C_ij)/eps = 20*dot + wv_j + gx_i.
// MFMA 16x16x32: A-frag lane: A[m=lane&15][k=quad*8+..]; C/D: col=lane&15(=j),
// row=quad*4+reg(=i). Each lane tracks 4 online-LSE states (same 4 rows, all tiles).
__global__ __launch_bounds__(256) void urec_kernel(const short* __restrict__ xh,
                                                   const short* __restrict__ xl,
                                                   const short* __restrict__ yh,
                                                   const short* __restrict__ yl,
                                                   const float* __restrict__ gx,
                                                   const float* __restrict__ wv,
                                                   float* __restrict__ u,
                                                   float* __restrict__ wu,
                                                   float* __restrict__ errbuf,
                                                   const int* __restrict__ done_arr,
                                                   int it, float log_mu) {
  if (done_arr[it]) return;
  int batch = blockIdx.y;
  int i0 = blockIdx.x * 16;
  int t = threadIdx.x;
  int w = t >> 6, lane = t & 63;
  int quad = lane >> 4, lpos = lane & 15;

  const short* xhb = xh + ((size_t)batch * P + i0) * 32;
  const short* xlb = xl + ((size_t)batch * P + i0) * 32;
  bf16x8 xa = *(const bf16x8*)(xhb + lpos * 32 + quad * 8);
  bf16x8 xb = *(const bf16x8*)(xlb + lpos * 32 + quad * 8);

  float gr[4];
#pragma unroll
  for (int r = 0; r < 4; ++r) gr[r] = gx[batch * P + i0 + quad * 4 + r];

  const short* yhb = yh + (size_t)batch * P * 32;
  const short* ylb = yl + (size_t)batch * P * 32;
  const float* wvb = wv + batch * P;

  float m[4], s[4];
#pragma unroll
  for (int r = 0; r < 4; ++r) { m[r] = -1e30f; s[r] = 0.f; }

  for (int tt = 0; tt < 48; ++tt) {
    int j0t = w * 768 + tt * 16;
    bf16x8 ya = *(const bf16x8*)(yhb + (size_t)(j0t + lpos) * 32 + quad * 8);
    bf16x8 yb = *(const bf16x8*)(ylb + (size_t)(j0t + lpos) * 32 + quad * 8);
    f32x4 acc = {0.f, 0.f, 0.f, 0.f};
    acc = __builtin_amdgcn_mfma_f32_16x16x32_bf16(xa, ya, acc, 0, 0, 0);
    acc = __builtin_amdgcn_mfma_f32_16x16x32_bf16(xa, yb, acc, 0, 0, 0);
    acc = __builtin_amdgcn_mfma_f32_16x16x32_bf16(xb, ya, acc, 0, 0, 0);
    float wvj = wvb[j0t + lpos];
#pragma unroll
    for (int r = 0; r < 4; ++r) {
      float a = fmaf(20.f, acc[r], wvj + gr[r]);
      float n = fmaxf(m[r], a);
      s[r] = s[r] * __expf(m[r] - n) + __expf(a - n);
      m[r] = n;
    }
  }
  // merge across the 16 lanes sharing this quad (different j, same rows)
#pragma unroll
  for (int mask = 1; mask <= 8; mask <<= 1) {
#pragma unroll
    for (int r = 0; r < 4; ++r) {
      float om = __shfl_xor(m[r], mask, 64);
      float os = __shfl_xor(s[r], mask, 64);
      float M = fmaxf(m[r], om);
      s[r] = s[r] * __expf(m[r] - M) + os * __expf(om - M);
      m[r] = M;
    }
  }
  __shared__ float lm[4][16];
  __shared__ float ls[4][16];
  if (lpos == 0) {
#pragma unroll
    for (int r = 0; r < 4; ++r) { lm[w][quad * 4 + r] = m[r]; ls[w][quad * 4 + r] = s[r]; }
  }
  __syncthreads();
  if (t < 16) {
    float M = fmaxf(fmaxf(lm[0][t], lm[1][t]), fmaxf(lm[2][t], lm[3][t]));
    float S = ls[0][t] * __expf(lm[0][t] - M) + ls[1][t] * __expf(lm[1][t] - M) +
              ls[2][t] * __expf(lm[2][t] - M) + ls[3][t] * __expf(lm[3][t] - M);
    float L = M + __logf(S);
    float un = 0.1f * log_mu - 0.1f * L;
    int gi = batch * P + i0 + t;
    float uo = u[gi];
    u[gi] = un;
    wu[gi] = fmaf(10.f, un, gx[gi]);
    errbuf[gi] = fabsf(un - uo);
  }
}

// v-update (mirror): a_ij = (u_i - C_ij)/eps = 20*dot + wu_i + gy_j.
// A-frag from y (m=j), B-frag from x (n=i). Block = 16 cols; waves split i.
// Block (0,0) also evaluates convergence -> done_arr[it+1].
__global__ __launch_bounds__(256) void vrec_kernel(const short* __restrict__ xh,
                                                   const short* __restrict__ xl,
                                                   const short* __restrict__ yh,
                                                   const short* __restrict__ yl,
                                                   const float* __restrict__ gy,
                                                   const float* __restrict__ wu,
                                                   float* __restrict__ v,
                                                   float* __restrict__ wv,
                                                   const float* __restrict__ errbuf,
                                                   int* __restrict__ done_arr,
                                                   int it, float log_nu) {
  int dn = done_arr[it];
  int t = threadIdx.x;
  if (!dn) {
    int batch = blockIdx.y;
    int j0 = blockIdx.x * 16;
    int w = t >> 6, lane = t & 63;
    int quad = lane >> 4, lpos = lane & 15;

    const short* yhb = yh + ((size_t)batch * P + j0) * 32;
    const short* ylb = yl + ((size_t)batch * P + j0) * 32;
    bf16x8 ya = *(const bf16x8*)(yhb + lpos * 32 + quad * 8);
    bf16x8 yb = *(const bf16x8*)(ylb + lpos * 32 + quad * 8);

    float gr[4];
#pragma unroll
    for (int r = 0; r < 4; ++r) gr[r] = gy[batch * P + j0 + quad * 4 + r];

    const short* xhb = xh + (size_t)batch * P * 32;
    const short* xlb = xl + (size_t)batch * P * 32;
    const float* wub = wu + batch * P;

    float m[4], s[4];
#pragma unroll
    for (int r = 0; r < 4; ++r) { m[r] = -1e30f; s[r] = 0.f; }

    for (int tt = 0; tt < 48; ++tt) {
      int i0t = w * 768 + tt * 16;
      bf16x8 xa = *(const bf16x8*)(xhb + (size_t)(i0t + lpos) * 32 + quad * 8);
      bf16x8 xb = *(const bf16x8*)(xlb + (size_t)(i0t + lpos) * 32 + quad * 8);
      f32x4 acc = {0.f, 0.f, 0.f, 0.f};
      acc = __builtin_amdgcn_mfma_f32_16x16x32_bf16(ya, xa, acc, 0, 0, 0);
      acc = __builtin_amdgcn_mfma_f32_16x16x32_bf16(ya, xb, acc, 0, 0, 0);
      acc = __builtin_amdgcn_mfma_f32_16x16x32_bf16(yb, xa, acc, 0, 0, 0);
      float wui = wub[i0t + lpos];
#pragma unroll
      for (int r = 0; r < 4; ++r) {
        float a = fmaf(20.f, acc[r], wui + gr[r]);
        float n = fmaxf(m[r], a);
        s[r] = s[r] * __expf(m[r] - n) + __expf(a - n);
        m[r] = n;
      }
    }
#pragma unroll
    for (int mask = 1; mask <= 8; mask <<= 1) {
#pragma unroll
      for (int r = 0; r < 4; ++r) {
        float om = __shfl_xor(m[r], mask, 64);
        float os = __shfl_xor(s[r], mask, 64);
        float M = fmaxf(m[r], om);
        s[r] = s[r] * __expf(m[r] - M) + os * __expf(om - M);
        m[r] = M;
      }
    }
    __shared__ float lm[4][16];
    __shared__ float ls[4][16];
    if (lpos == 0) {
#pragma unroll
      for (int r = 0; r < 4; ++r) { lm[w][quad * 4 + r] = m[r]; ls[w][quad * 4 + r] = s[r]; }
    }
    __syncthreads();
    if (t < 16) {
      float M = fmaxf(fmaxf(lm[0][t], lm[1][t]), fmaxf(lm[2][t], lm[3][t]));
      float S = ls[0][t] * __expf(lm[0][t] - M) + ls[1][t] * __expf(lm[1][t] - M) +
                ls[2][t] * __expf(lm[2][t] - M) + ls[3][t] * __expf(lm[3][t] - M);
      float L = M + __logf(S);
      float vn = 0.1f * log_nu - 0.1f * L;
      int gj = batch * P + j0 + t;
      v[gj] = vn;
      wv[gj] = fmaf(10.f, vn, gy[gj]);
    }
  }
  // convergence flag for it+1 (errbuf written by urec(it) earlier in stream)
  if (blockIdx.x == 0 && blockIdx.y == 0) {
    __shared__ float red[4];
    float loc = 0.f;
    if (!dn) {
      for (int idx = t; idx < NROW; idx += 256) loc += errbuf[idx];
    }
    loc = waveReduceSum(loc);
    if ((t & 63) == 0) red[t >> 6] = loc;
    __syncthreads();
    if (t == 0) {
      float tot = red[0] + red[1] + red[2] + red[3];
      done_arr[it + 1] = (dn || (tot * 0.25f < 0.1f)) ? 1 : 0;
    }
  }
}

// pi = exp((-C + u_i + v_j)/eps) from the exact stored C; fused cost atomics.
__global__ __launch_bounds__(256) void pi_kernel(const float* __restrict__ C,
                                                 const float* __restrict__ u,
                                                 const float* __restrict__ v,
                                                 float* __restrict__ pi,
                                                 float* __restrict__ cost) {
  int bi = blockIdx.x;
  int b = bi / P;
  float ui = u[bi];
  const float4* Crow = (const float4*)(C + (size_t)bi * P);
  const float4* v4 = (const float4*)(v + (size_t)b * P);
  float4* pirow = (float4*)(pi + (size_t)bi * P);
  int t = threadIdx.x;
  float acc = 0.f;
#pragma unroll
  for (int k = 0; k < 3; ++k) {
    float4 c = Crow[t + k * 256];
    float4 vv = v4[t + k * 256];
    float4 p;
    p.x = __expf((ui + vv.x - c.x) * 10.f);
    p.y = __expf((ui + vv.y - c.y) * 10.f);
    p.z = __expf((ui + vv.z - c.z) * 10.f);
    p.w = __expf((ui + vv.w - c.w) * 10.f);
    pirow[t + k * 256] = p;
    acc += p.x * c.x + p.y * c.y + p.z * c.z + p.w * c.w;
  }
  acc = waveReduceSum(acc);
  __shared__ float red[4];
  if ((t & 63) == 0) red[t >> 6] = acc;
  __syncthreads();
  if (t == 0) atomicAdd(&cost[b], red[0] + red[1] + red[2] + red[3]);
}

extern "C" void kernel_launch(void* const* d_in, const int* in_sizes, int n_in,
                              void* d_out, int out_size, void* d_ws, size_t ws_size,
                              hipStream_t stream) {
  (void)in_sizes; (void)n_in; (void)out_size; (void)ws_size;
  const float* x = (const float*)d_in[0];
  const float* y = (const float*)d_in[1];
  float* out = (float*)d_out;
  float* cost = out;                          // [4]
  float* pi = out + 4;                        // [4*3072*3072]
  float* C = pi + (size_t)BATCH * P * P;      // [4*3072*3072]

  // bf16 split arrays live in the pi output region (scratch until pi_kernel,
  // which runs after the last vrec_kernel read of them).
  short* xh = (short*)pi;                     // SPLIT_N shorts
  short* xl = xh + SPLIT_N;
  short* yh = xl + SPLIT_N;
  short* yl = yh + SPLIT_N;

  // workspace (floats):
  float* u = (float*)d_ws;                    // 12288  (zero-init)
  int* done_arr = (int*)(u + NROW);           // 64 ints (zero-init)
  float* v = (float*)(done_arr + 64);         // 12288
  float* x2 = v + NROW;                       // 12288
  float* y2 = x2 + NROW;                      // 12288
  float* gx = y2 + NROW;                      // 12288
  float* gy = gx + NROW;                      // 12288
  float* wu = gy + NROW;                      // 12288
  float* wv = wu + NROW;                      // 12288
  float* errbuf = wv + NROW;                  // 12288

  hipMemsetAsync(d_ws, 0, (size_t)(NROW + 64) * sizeof(float), stream);
  hipMemsetAsync(cost, 0, 4 * sizeof(float), stream);

  float log_mu = logf(1.0f / 3072.0f + 1e-8f);   // log_nu identical (P1==P2)

  split_kernel<<<2 * SPLIT_N / 256, 256, 0, stream>>>(x, y, xh, xl, yh, yl);
  sq_kernel<<<3072, 256, 0, stream>>>(x, y, x2, y2, gx, gy, wu, wv);
  c_kernel<<<dim3(48, 48, 4), 256, 0, stream>>>(x, y, x2, y2, C);

  for (int it = 0; it < MAXIT; ++it) {
    urec_kernel<<<dim3(192, 4), 256, 0, stream>>>(xh, xl, yh, yl, gx, wv,
                                                  u, wu, errbuf, done_arr, it, log_mu);
    vrec_kernel<<<dim3(192, 4), 256, 0, stream>>>(xh, xl, yh, yl, gy, wu,
                                                  v, wv, errbuf, done_arr, it, log_mu);
  }

  pi_kernel<<<NROW, 256, 0, stream>>>(C, u, v, pi, cost);
}